// Round 8
// baseline (878.270 us; speedup 1.0000x reference)
//
#include <hip/hip_runtime.h>
#include <hip/hip_bf16.h>
#include <hip/hip_fp16.h>

typedef __hip_bfloat16 bf16;
typedef __attribute__((ext_vector_type(8))) short short8v;
typedef __attribute__((ext_vector_type(4))) float float4v;

#define V_    32000
#define E_    512
#define H_    512
#define T_    128
#define B_    4
#define D_    4
#define L_    2
#define C0_   2000
#define C1_   10000
#define NT_   125
#define NROW_ 2000          // B*NT*D
#define NH_   2002
#define NTOTC 2162          // 2002 + 128 + 32
#define NSLOT 252           // LSE partial slots per row
// slot map (slot-major lsep): head 0..16, t0 17..79, t1 80..251
#define SB_T0 17
#define SB_T1 80

__device__ __forceinline__ float bf2f(bf16 v) { return __bfloat162float(v); }
__device__ __forceinline__ unsigned short f2bfu(float f) {
    bf16 h = __float2bfloat16(f);
    union { bf16 h; unsigned short u; } cv; cv.h = h; return cv.u;
}
// dtype-flag helpers: bf==1 -> bf16 input data, bf==0 -> float32
__device__ __forceinline__ float ld1(const void* p, size_t i, int bf) {
    return bf ? bf2f(((const bf16*)p)[i]) : ((const float*)p)[i];
}

__device__ __forceinline__ void lse_push(float z, float& m, float& s) {
    if (z <= m) { s += __expf(z - m); }
    else        { s = s * __expf(m - z) + 1.0f; m = z; }
}
__device__ __forceinline__ void lse_merge(float m2, float s2, float& m, float& s) {
    float mm = fmaxf(m, m2);
    s = s * __expf(m - mm) + s2 * __expf(m2 - mm);
    m = mm;
}

// ---------------- weight conversion + embedding gather (merged) -----------
// dtype detect inlined per-block (G row 0 is a softmax row; sum==1 -> fp32).
// Block 0 publishes the flag for later kernels. Conversion is 4-wide
// vectorized: every segment offset is a multiple of 4 shorts.
struct ConvArgs {
    const void* src[9];
    unsigned int off[10];
};
__global__ void k_wembed(ConvArgs a, unsigned short* __restrict__ wb,
                         int* __restrict__ flagp,
                         const int* __restrict__ x, const void* __restrict__ emb,
                         float* __restrict__ embedded, float* __restrict__ f0,
                         unsigned short* __restrict__ f0b,
                         const void* __restrict__ G) {
    __shared__ int s_bf;
    if (threadIdx.x < 64) {
        float s32 = ((const float*)G)[threadIdx.x] + ((const float*)G)[threadIdx.x + 64];
        for (int off = 32; off; off >>= 1) s32 += __shfl_down(s32, off);
        if (threadIdx.x == 0) {
            int v = (fabsf(s32 - 1.0f) < 0.05f) ? 0 : 1;  // NaN-safe: bf16 fallback
            s_bf = v;
            if (blockIdx.x == 0) *flagp = v;
        }
    }
    __syncthreads();
    const int bf = s_bf;
    if (blockIdx.x < 1024) {
        // embedding gather: 262144 elements
        int i = blockIdx.x * 256 + threadIdx.x;
        int bt = i >> 9, e = i & 511;
        int tok = x[bt];
        float v = ld1(emb, (size_t)tok * E_ + e, bf);
        embedded[i] = v; f0[i] = v; f0b[i] = f2bfu(v);
    } else {
        unsigned int totalg = a.off[9] >> 2;          // groups of 4 shorts
        unsigned int stride = (gridDim.x - 1024) * 256;
        for (unsigned int g = (blockIdx.x - 1024) * 256 + threadIdx.x; g < totalg;
             g += stride) {
            unsigned int i = g << 2;
            int seg = 0;
            while (i >= a.off[seg + 1]) seg++;
            unsigned int o = i - a.off[seg];
            unsigned short r[4];
            if (bf) {
                *(uint2*)r = *(const uint2*)((const unsigned short*)a.src[seg] + o);
            } else {
                float4 v = *(const float4*)((const float*)a.src[seg] + o);
                r[0] = f2bfu(v.x); r[1] = f2bfu(v.y);
                r[2] = f2bfu(v.z); r[3] = f2bfu(v.w);
            }
            *(uint2*)(wb + i) = *(const uint2*)r;
        }
    }
}

// ---------------- wgt[b,i,e] = sum_j G[b,l,j,i] f[b,j,e] ------------------
__global__ void k_wgt(const void* __restrict__ G, const float* __restrict__ f,
                      unsigned short* __restrict__ wgtb, int l,
                      const int* __restrict__ flagp) {
    const int bf = *flagp;
    int i = blockIdx.x * 256 + threadIdx.x;          // 262144
    int e = i & 511;
    int bi = i >> 9;
    int b = bi >> 7, ip = bi & 127;
    size_t gbase = ((size_t)(b * L_ + l) * T_ * T_) + ip;
    const float* fb = f + (size_t)b * T_ * E_ + e;
    float acc = 0.0f;
    #pragma unroll 4
    for (int j = 0; j < T_; ++j)
        acc = fmaf(ld1(G, gbase + (size_t)j * T_, bf), fb[(size_t)j * E_], acc);
    wgtb[i] = f2bfu(acc);
}

// ---------------- MFMA bf16 GEMM: Z[M,N] = A[M,K] * W[N,K]^T --------------
// MODE 0: gates (store Z+bias into Zg at col zsel*zcol1; blockIdx.z picks A/W/bias)
// MODE 1: head single-pass (raw z -> out-in-place for cols<C0; stats 2000/2001;
//         proj -> p0b/p1b; LSE cols<2002 -> lsep)
// MODE 2: tail single-pass (raw z -> out-in-place at outColOff; LSE over all N)
// Raw-logit staging: fp16 slots when out dtype is bf16, fp32 when fp32 —
// d_out is exactly the right size in both modes. lsep is slot-major
// [slot][row] so the corr reduction in k_fix coalesces.
struct GemmP {
    const unsigned short* A0;
    const unsigned short* A1;
    const unsigned short* W;
    unsigned long long w1off;
    int M, N, K, Nlse;
    float* Zg; int ldz; int zcol1;
    const void* bias0; const void* bias1; int boff;
    void* zraw; int outColOff;
    float* stats;
    unsigned short* p0b;
    unsigned short* p1b;
    float* lsep; int slotBase;
    const int* lengths;
    const int* flagp;
    int gx;       // x-tile count of this segment (merged tail dispatch)
};

__device__ __forceinline__ void zstore(void* zraw, size_t i, int bf, float v) {
    if (bf) ((__half*)zraw)[i] = __float2half(v);
    else    ((float*)zraw)[i]  = v;
}

template<int MODE>
__device__ __forceinline__ void gemm_core(const GemmP& p, int bx, int by,
        unsigned short* As, unsigned short* Bs,
        float (*pm)[2], float (*ps)[2]) {
    const int bf = *p.flagp;
    const int zsel = (MODE == 0) ? blockIdx.z : 0;
    const unsigned short* A  = zsel ? p.A1 : p.A0;
    const unsigned short* Bw = p.W + (zsel ? p.w1off : 0ull);
    const int M = p.M, N = p.N, K = p.K;
    const int m0 = by * 128, n0 = bx * 128;
    const int t = threadIdx.x;
    const int wave = t >> 6, lane = t & 63;
    const int wm = wave >> 1, wn = wave & 1;
    const int quad = lane >> 4, l16 = lane & 15;

    float4v acc[4][4];
    #pragma unroll
    for (int mi = 0; mi < 4; ++mi)
        #pragma unroll
        for (int ni = 0; ni < 4; ++ni)
            acc[mi][ni] = (float4v){0.f, 0.f, 0.f, 0.f};

    for (int k0 = 0; k0 < K; k0 += 32) {
        if (k0) __syncthreads();
        #pragma unroll
        for (int i = 0; i < 2; ++i) {
            int idx = t + i * 256;
            int row = idx >> 2, seg = idx & 3;
            uint4 av = {0u, 0u, 0u, 0u};
            int gm = m0 + row;
            if (gm < M) av = *(const uint4*)(A + (size_t)gm * K + k0 + seg * 8);
            *(uint4*)(&As[row * 40 + seg * 8]) = av;
            uint4 bv = {0u, 0u, 0u, 0u};
            int gn = n0 + row;
            if (gn < N) bv = *(const uint4*)(Bw + (size_t)gn * K + k0 + seg * 8);
            *(uint4*)(&Bs[row * 40 + seg * 8]) = bv;
        }
        __syncthreads();
        short8v af[4], bfv[4];
        #pragma unroll
        for (int mi = 0; mi < 4; ++mi)
            af[mi] = *(const short8v*)(As + (wm * 64 + mi * 16 + l16) * 40 + quad * 8);
        #pragma unroll
        for (int ni = 0; ni < 4; ++ni)
            bfv[ni] = *(const short8v*)(Bs + (wn * 64 + ni * 16 + l16) * 40 + quad * 8);
        #pragma unroll
        for (int mi = 0; mi < 4; ++mi)
            #pragma unroll
            for (int ni = 0; ni < 4; ++ni)
                acc[mi][ni] = __builtin_amdgcn_mfma_f32_16x16x32_bf16(
                    af[mi], bfv[ni], acc[mi][ni], 0, 0, 0);
    }

    // ---- epilogue ----
    if (MODE == 0) {
        const void* bias = zsel ? p.bias1 : p.bias0;
        const int zcol = zsel ? p.zcol1 : 0;
        #pragma unroll
        for (int mi = 0; mi < 4; ++mi)
            #pragma unroll
            for (int r = 0; r < 4; ++r) {
                int grow = m0 + wm * 64 + mi * 16 + quad * 4 + r;
                if (grow >= M) continue;
                #pragma unroll
                for (int ni = 0; ni < 4; ++ni) {
                    int gcol = n0 + wn * 64 + ni * 16 + l16;
                    if (gcol < N)
                        p.Zg[(size_t)grow * p.ldz + zcol + gcol] =
                            acc[mi][ni][r] + ld1(bias, p.boff + gcol, bf);
                }
            }
    } else if (MODE == 1) {
        #pragma unroll
        for (int mi = 0; mi < 4; ++mi)
            #pragma unroll
            for (int r = 0; r < 4; ++r) {
                int grow = m0 + wm * 64 + mi * 16 + quad * 4 + r;
                if (grow >= M) continue;
                #pragma unroll
                for (int ni = 0; ni < 4; ++ni) {
                    int gcol = n0 + wn * 64 + ni * 16 + l16;
                    float v = acc[mi][ni][r];
                    if (gcol < C0_) zstore(p.zraw, (size_t)grow * V_ + gcol, bf, v);
                    else if (gcol < NH_) p.stats[grow * 8 + 2 + (gcol - C0_)] = v;
                    else if (gcol < 2130) p.p0b[grow * 128 + (gcol - NH_)] = f2bfu(v);
                    else if (gcol < NTOTC) p.p1b[grow * 32 + (gcol - 2130)] = f2bfu(v);
                }
            }
    } else {
        #pragma unroll
        for (int mi = 0; mi < 4; ++mi)
            #pragma unroll
            for (int r = 0; r < 4; ++r) {
                int grow = m0 + wm * 64 + mi * 16 + quad * 4 + r;
                if (grow >= M) continue;
                #pragma unroll
                for (int ni = 0; ni < 4; ++ni) {
                    int gcol = n0 + wn * 64 + ni * 16 + l16;
                    if (gcol < N)
                        zstore(p.zraw, (size_t)grow * V_ + p.outColOff + gcol, bf,
                               acc[mi][ni][r]);
                }
            }
    }

    // ---- fused per-tile LSE partials (single-pass modes) ----
    if (MODE == 1 || MODE == 2) {
        const int Nlse = p.Nlse;
        #pragma unroll
        for (int mi = 0; mi < 4; ++mi) {
            #pragma unroll
            for (int r = 0; r < 4; ++r) {
                float m = -1e30f, s = 0.0f;
                #pragma unroll
                for (int ni = 0; ni < 4; ++ni) {
                    int gcol = n0 + wn * 64 + ni * 16 + l16;
                    if (gcol < Nlse) lse_push(acc[mi][ni][r], m, s);
                }
                #pragma unroll
                for (int off = 1; off < 16; off <<= 1) {
                    float m2 = __shfl_xor(m, off), s2 = __shfl_xor(s, off);
                    lse_merge(m2, s2, m, s);
                }
                if (l16 == 0) {
                    int rl = wm * 64 + mi * 16 + quad * 4 + r;
                    pm[rl][wn] = m; ps[rl][wn] = s;
                }
            }
        }
        __syncthreads();
        if (t < 128) {
            int grow = m0 + t;
            if (grow < M) {
                float m = pm[t][0], s = ps[t][0];
                lse_merge(pm[t][1], ps[t][1], m, s);
                // slot-major layout: [slot][row]
                float* dst = p.lsep + ((size_t)(p.slotBase + bx) * NROW_ + grow) * 2;
                dst[0] = m; dst[1] = s;
            }
        }
    }
}

// __launch_bounds__(256, 2): 4 waves/block, min 2 waves/EU -> VGPR cap 256.
// Single-instantiation GEMM kernels compile clean (r2-r5); 3-way merged
// variants spill regardless of bounds/waves_per_eu pins (r1, r6, r7) —
// reverted to this proven structure.
template<int MODE>
__global__ __launch_bounds__(256, 2) void k_gemm(GemmP p) {
    __shared__ __align__(16) unsigned short As[128 * 40];
    __shared__ __align__(16) unsigned short Bs[128 * 40];
    __shared__ float pm[128][2], ps[128][2];
    gemm_core<MODE>(p, blockIdx.x, blockIdx.y, As, Bs, pm, ps);
}

// merged t0+t1 pass-A tail (both depend only on the head pass; independent
// of each other, so co-dispatch is race-free and fills the t0 tail).
// Both segments are the SAME instantiation gemm_core<2> — this 2-way form
// was clean at r5 (766 µs), unlike the 3-way <1>+<2> merge.
__global__ __launch_bounds__(256, 2) void k_gemmT(GemmP pa, GemmP pb) {
    __shared__ __align__(16) unsigned short As[128 * 40];
    __shared__ __align__(16) unsigned short Bs[128 * 40];
    __shared__ float pm[128][2], ps[128][2];
    int bx = blockIdx.x;
    if (bx < pa.gx) gemm_core<2>(pa, bx, blockIdx.y, As, Bs, pm, ps);
    else            gemm_core<2>(pb, bx - pa.gx, blockIdx.y, As, Bs, pm, ps);
}

// ---------------- GRU pointwise ----------------
__device__ __forceinline__ float gru2(float i_r, float i_z, float i_n,
                                      float h_r, float h_z, float h_n, float h) {
    float r = 1.0f / (1.0f + __expf(-(i_r + h_r)));
    float z = 1.0f / (1.0f + __expf(-(i_z + h_z)));
    float n = tanhf(i_n + r * h_n);
    return (1.0f - z) * n + z * h;
}

__global__ void k_apply_enc(const float* __restrict__ gates,
                            const float* __restrict__ hprev,
                            float* __restrict__ hnext,
                            unsigned short* __restrict__ hnextb) {
    int i = blockIdx.x * 256 + threadIdx.x;          // 262144
    int row = i >> 9, k = i & 511;
    const float* g = gates + (size_t)row * 3072;
    float v = gru2(g[k], g[512 + k], g[1024 + k],
                   g[1536 + k], g[2048 + k], g[2560 + k], hprev[i]);
    hnext[i] = v; hnextb[i] = f2bfu(v);
}

// layer-1 apply fused with decoder prep: h0 init straight from the value in
// registers (blocks <1024) + window gather (blocks 1024..5023).
__global__ void k_apply_enc2(const float* __restrict__ gates,
                             const float* __restrict__ hprev,
                             float* __restrict__ hnext,
                             unsigned short* __restrict__ hnextb,
                             const float* __restrict__ embedded,
                             const int* __restrict__ lengths,
                             unsigned short* __restrict__ winb,
                             float* __restrict__ hdec,
                             unsigned short* __restrict__ hdecb) {
    int blk = blockIdx.x;
    if (blk < 1024) {
        int i = blk * 256 + threadIdx.x;             // 262144
        int row = i >> 9, k = i & 511;
        const float* g = gates + (size_t)row * 3072;
        float v = gru2(g[k], g[512 + k], g[1024 + k],
                       g[1536 + k], g[2048 + k], g[2560 + k], hprev[i]);
        hnext[i] = v; hnextb[i] = f2bfu(v);
        int b = row >> 7, t = row & 127;
        if (t < NT_) {
            int j = ((b * NT_ + t) << 9) + k;
            hdec[j] = v; hdecb[j] = f2bfu(v);
        }
    } else {
        int i = (blk - 1024) * 256 + threadIdx.x;    // 1,024,000
        int e = i & 511;
        int wr = i >> 9;
        int d = wr / 500, row = wr - d * 500;
        int b = row / NT_, t = row - b * NT_;
        int tok = (d == 0 && t == 0) ? (lengths[b] - 1) : (t + d - 1);
        winb[i] = f2bfu(embedded[((size_t)(b * T_ + tok) << 9) + e]);
    }
}

__global__ void k_apply_dec(const float* __restrict__ gih,
                            const float* __restrict__ ghh,
                            float* __restrict__ hdec,
                            unsigned short* __restrict__ hdecb,
                            unsigned short* __restrict__ hsb,
                            const int* __restrict__ lengths, int d) {
    int i = blockIdx.x * 256 + threadIdx.x;          // 256000
    int row = i >> 9, k = i & 511;
    int b = row / NT_, t = row - b * NT_;
    const float* gi = gih + (size_t)(d * 500 + row) * 1536;
    const float* gh = ghh + (size_t)row * 1536;
    float hn = gru2(gi[k], gi[512 + k], gi[1024 + k],
                    gh[k], gh[512 + k], gh[1024 + k], hdec[i]);
    hdec[i] = hn; hdecb[i] = f2bfu(hn);
    bool valid = (t + d) < lengths[b];
    hsb[(((size_t)row * D_ + d) << 9) + k] = valid ? f2bfu(hn) : (unsigned short)0;
}

// ------ in-place fixup with inline per-row LSE correction -----------------
// out[i] = valid ? zraw[i] - corr[seg(i)] : 0.  Raw logits were staged into
// d_out itself.  Each block touches at most 2 rows (256 thr x 8 cols = 2048
// cols < V); wave w (w<2) computes row (row0+w)'s three corrections via a
// 64-lane butterfly LSE merge over the slot-major lsep partials (coalesced).
__global__ void k_fix(const float* __restrict__ lsep, const float* __restrict__ stats,
                      const int* __restrict__ lengths, void* __restrict__ out,
                      const int* __restrict__ flagp) {
    const int bf = *flagp;
    const int GPR = V_ / 8;                          // 4000 groups per row
    int firstIdx = blockIdx.x * 256;
    int row0 = firstIdx / GPR;
    int rowLast = (firstIdx + 255) / GPR;            // row0 or row0+1
    __shared__ float scorr[2][4];
    int w = threadIdx.x >> 6, lane = threadIdx.x & 63;
    if (w <= rowLast - row0 && w < 2) {
        int r = row0 + w;
        float mh = -1e30f, sh = 0.f, m0 = -1e30f, s0 = 0.f, m1 = -1e30f, s1 = 0.f;
        if (lane < 17) {
            const float* P = lsep + ((size_t)lane * NROW_ + r) * 2;
            mh = P[0]; sh = P[1];
        }
        if (lane < 63) {
            const float* P = lsep + ((size_t)(SB_T0 + lane) * NROW_ + r) * 2;
            m0 = P[0]; s0 = P[1];
        }
        for (int j = lane; j < 172; j += 64) {
            const float* P = lsep + ((size_t)(SB_T1 + j) * NROW_ + r) * 2;
            lse_merge(P[0], P[1], m1, s1);
        }
        #pragma unroll
        for (int off = 32; off; off >>= 1) {
            lse_merge(__shfl_xor(mh, off), __shfl_xor(sh, off), mh, sh);
            lse_merge(__shfl_xor(m0, off), __shfl_xor(s0, off), m0, s0);
            lse_merge(__shfl_xor(m1, off), __shfl_xor(s1, off), m1, s1);
        }
        if (lane == 0) {
            float ch  = mh + logf(sh);
            float ct0 = m0 + logf(s0);
            float ct1 = m1 + logf(s1);
            scorr[w][0] = ch;
            scorr[w][1] = ct0 - (stats[r * 8 + 2] - ch);
            scorr[w][2] = ct1 - (stats[r * 8 + 3] - ch);
        }
    }
    __syncthreads();
    int idx = firstIdx + threadIdx.x;
    int row = idx / GPR;
    int col = (idx - row * GPR) * 8;
    int b = row / 500;
    int tt = (row - b * 500) >> 2;
    bool valid = tt < lengths[b];
    int cri = (col < C0_) ? 0 : (col < C1_ ? 1 : 2);
    float cr = scorr[row - row0][cri];
    size_t base = (size_t)row * V_ + col;
    if (bf) {
        unsigned short* p16 = (unsigned short*)out + base;
        union { uint4 u; __half h[8]; } in;
        in.u = *(const uint4*)p16;
        union { uint4 u; unsigned short s[8]; } o;
        #pragma unroll
        for (int j = 0; j < 8; ++j)
            o.s[j] = f2bfu(valid ? (__half2float(in.h[j]) - cr) : 0.0f);
        *(uint4*)p16 = o.u;
    } else {
        float* op = (float*)out + base;
        float4 a = *(float4*)op, c = *(float4*)(op + 4);
        float4 ra = valid ? (float4){a.x - cr, a.y - cr, a.z - cr, a.w - cr}
                          : (float4){0.f, 0.f, 0.f, 0.f};
        float4 rc = valid ? (float4){c.x - cr, c.y - cr, c.z - cr, c.w - cr}
                          : (float4){0.f, 0.f, 0.f, 0.f};
        *(float4*)op = ra; *(float4*)(op + 4) = rc;
    }
}

// ---------------- workspace layout (float offsets, 16B aligned) -----------
#define OFF_EMB    0u          // 262144
#define OFF_FA     262144u     // 262144
#define OFF_FB     524288u     // 262144
#define OFF_FAB    786432u     // 131072 (262144 bf16)
#define OFF_FBB    917504u     // 131072
#define OFF_WGTB   1048576u    // 131072
#define OFF_GATES  1179648u    // 512*3072 = 1572864
#define OFF_GIH    2752512u    // 2000*1536 = 3072000
#define OFF_GHH    5824512u    // 500*1536 = 768000
#define OFF_HDEC   6592512u    // 256000
#define OFF_HDECB  6848512u    // 128000
#define OFF_WINB   6976512u    // 512000 (1,024,000 bf16)
#define OFF_HSB    7488512u    // 512000 (1,024,000 bf16)
#define OFF_P0B    8000512u    // 128000 (256000 bf16)
#define OFF_P1B    8128512u    // 32000  (64000 bf16)
#define OFF_STATS  8160512u    // 16000
#define OFF_LSEP   8184512u    // 1008000 (slot-major 252 x 2000 x 2)
#define OFF_WB     9192512u    // 3776752 (7553504 bf16)
#define OFF_FLAG   12969264u

// bf16 weight region sub-offsets (shorts)
#define WO_ENCIH   0u
#define WO_ENCHH   1572864u
#define WO_DECIH   3145728u
#define WO_DECHH   3932160u
#define WO_W1      4718592u    // head_w rows, t0_proj, t1_proj (2162x512)
#define WO_T0O     5825536u    // 8000x128
#define WO_T1O     6849536u    // 22000x32
#define WO_END     7553504u

static inline GemmP mkp(const unsigned short* A0, const unsigned short* A1,
                        const unsigned short* W, unsigned long long w1off,
                        int M, int N, int K, int Nlse,
                        float* Zg, int ldz, int zcol1,
                        const void* bias0, const void* bias1, int boff,
                        void* zraw, int outColOff, float* stats,
                        unsigned short* p0b, unsigned short* p1b,
                        float* lsep, int slotBase,
                        const int* lengths, const int* flagp) {
    GemmP p;
    p.A0 = A0; p.A1 = A1; p.W = W; p.w1off = w1off;
    p.M = M; p.N = N; p.K = K; p.Nlse = Nlse;
    p.Zg = Zg; p.ldz = ldz; p.zcol1 = zcol1;
    p.bias0 = bias0; p.bias1 = bias1; p.boff = boff;
    p.zraw = zraw; p.outColOff = outColOff; p.stats = stats;
    p.p0b = p0b; p.p1b = p1b; p.lsep = lsep; p.slotBase = slotBase;
    p.lengths = lengths; p.flagp = flagp; p.gx = 0;
    return p;
}

extern "C" void kernel_launch(void* const* d_in, const int* in_sizes, int n_in,
                              void* d_out, int out_size, void* d_ws, size_t ws_size,
                              hipStream_t stream) {
    (void)in_sizes; (void)n_in; (void)out_size; (void)ws_size;
    const int*  x        = (const int*)d_in[0];
    const int*  lengths  = (const int*)d_in[1];
    const void* G        = d_in[2];
    const void* emb      = d_in[3];
    const void* enc_w_ih = d_in[4];
    const void* enc_w_hh = d_in[5];
    const void* enc_b_ih = d_in[6];
    const void* enc_b_hh = d_in[7];
    const void* dec_w_ih = d_in[8];
    const void* dec_w_hh = d_in[9];
    const void* dec_b_ih = d_in[10];
    const void* dec_b_hh = d_in[11];
    const void* head_w   = d_in[12];
    const void* t0_proj  = d_in[13];
    const void* t0_out   = d_in[14];
    const void* t1_proj  = d_in[15];
    const void* t1_out   = d_in[16];

    float* ws = (float*)d_ws;
    float* embedded = ws + OFF_EMB;
    float* fA    = ws + OFF_FA;
    float* fB    = ws + OFF_FB;
    unsigned short* fAb  = (unsigned short*)(ws + OFF_FAB);
    unsigned short* fBb  = (unsigned short*)(ws + OFF_FBB);
    unsigned short* wgtb = (unsigned short*)(ws + OFF_WGTB);
    float* gates = ws + OFF_GATES;
    float* gih   = ws + OFF_GIH;
    float* ghh   = ws + OFF_GHH;
    float* hdec  = ws + OFF_HDEC;
    unsigned short* hdecb = (unsigned short*)(ws + OFF_HDECB);
    unsigned short* winb  = (unsigned short*)(ws + OFF_WINB);
    unsigned short* hsb   = (unsigned short*)(ws + OFF_HSB);
    unsigned short* p0b   = (unsigned short*)(ws + OFF_P0B);
    unsigned short* p1b   = (unsigned short*)(ws + OFF_P1B);
    float* stats = ws + OFF_STATS;
    float* lsep  = ws + OFF_LSEP;
    unsigned short* WB = (unsigned short*)(ws + OFF_WB);
    int* flagp = (int*)(ws + OFF_FLAG);
    void* out = d_out;

    ConvArgs ca;
    ca.src[0] = enc_w_ih; ca.src[1] = enc_w_hh; ca.src[2] = dec_w_ih;
    ca.src[3] = dec_w_hh; ca.src[4] = head_w;   ca.src[5] = t0_proj;
    ca.src[6] = t1_proj;  ca.src[7] = t0_out;   ca.src[8] = t1_out;
    ca.off[0] = WO_ENCIH; ca.off[1] = WO_ENCHH; ca.off[2] = WO_DECIH;
    ca.off[3] = WO_DECHH; ca.off[4] = WO_W1;
    ca.off[5] = WO_W1 + 2002u * 512u;
    ca.off[6] = WO_W1 + 2130u * 512u;
    ca.off[7] = WO_T0O;   ca.off[8] = WO_T1O;   ca.off[9] = WO_END;
    // inline dtype-detect (flag published by block 0 for later kernels)
    k_wembed<<<3072, 256, 0, stream>>>(ca, WB, flagp, x, emb, embedded, fA, fAb, G);

    // encoder layer 0: fA -> fB  (ih + hh fused via gridDim.z)
    k_wgt<<<1024, 256, 0, stream>>>(G, fA, wgtb, 0, flagp);
    k_gemm<0><<<dim3(12, 4, 2), 256, 0, stream>>>(mkp(
        wgtb, fAb, WB + WO_ENCIH, (unsigned long long)(WO_ENCHH - WO_ENCIH),
        512, 1536, 512, 0, gates, 3072, 1536, enc_b_ih, enc_b_hh, 0,
        nullptr, 0, nullptr, nullptr, nullptr, nullptr, 0, lengths, flagp));
    k_apply_enc<<<1024, 256, 0, stream>>>(gates, fA, fB, fBb);

    // encoder layer 1: fB -> fA, fused with decoder prep (h0 + window gather)
    k_wgt<<<1024, 256, 0, stream>>>(G, fB, wgtb, 1, flagp);
    k_gemm<0><<<dim3(12, 4, 2), 256, 0, stream>>>(mkp(
        wgtb, fBb, WB + WO_ENCIH + 786432u, (unsigned long long)(WO_ENCHH - WO_ENCIH),
        512, 1536, 512, 0, gates, 3072, 1536, enc_b_ih, enc_b_hh, 1536,
        nullptr, 0, nullptr, nullptr, nullptr, nullptr, 0, lengths, flagp));
    k_apply_enc2<<<5024, 256, 0, stream>>>(gates, fB, fA, fAb, embedded, lengths,
                                           winb, hdec, hdecb);

    // batched decoder ih GEMM (all 4 d-steps at once)
    k_gemm<0><<<dim3(12, 16, 1), 256, 0, stream>>>(mkp(
        winb, nullptr, WB + WO_DECIH, 0ull, 2000, 1536, 512, 0,
        gih, 1536, 0, dec_b_ih, nullptr, 0,
        nullptr, 0, nullptr, nullptr, nullptr, nullptr, 0, lengths, flagp));

    // serial decoder hh steps
    for (int d = 0; d < D_; ++d) {
        k_gemm<0><<<dim3(12, 4, 1), 256, 0, stream>>>(mkp(
            hdecb, nullptr, WB + WO_DECHH, 0ull, 500, 1536, 512, 0,
            ghh, 1536, 0, dec_b_hh, nullptr, 0,
            nullptr, 0, nullptr, nullptr, nullptr, nullptr, 0, lengths, flagp));
        k_apply_dec<<<1000, 256, 0, stream>>>(gih, ghh, hdec, hdecb, hsb, lengths, d);
    }

    // adaptive softmax — single pass: head (raw logits + stats + projections
    // + LSE partials), then t0+t1 tails merged into one dispatch
    k_gemm<1><<<dim3(17, 16, 1), 256, 0, stream>>>(mkp(
        hsb, nullptr, WB + WO_W1, 0ull, NROW_, NTOTC, 512, NH_,
        nullptr, 0, 0, nullptr, nullptr, 0, out, 0,
        stats, p0b, p1b, lsep, 0, lengths, flagp));
    {
        GemmP pa = mkp(p0b, nullptr, WB + WO_T0O, 0ull, NROW_, 8000, 128, 8000,
                       nullptr, 0, 0, nullptr, nullptr, 0, out, C0_,
                       stats, nullptr, nullptr, lsep, SB_T0, lengths, flagp);
        pa.gx = 63;
        GemmP pb = mkp(p1b, nullptr, WB + WO_T1O, 0ull, NROW_, 22000, 32, 22000,
                       nullptr, 0, 0, nullptr, nullptr, 0, out, C1_,
                       stats, nullptr, nullptr, lsep, SB_T1, lengths, flagp);
        pb.gx = 172;
        k_gemmT<<<dim3(235, 16, 1), 256, 0, stream>>>(pa, pb);
    }

    // in-place fixup with inline per-row corrections (k_corr2 fused in)
    k_fix<<<31250, 256, 0, stream>>>(lsep, stats, lengths, out, flagp);
}

// Round 9
// 765.990 us; speedup vs baseline: 1.1466x; 1.1466x over previous
//
#include <hip/hip_runtime.h>
#include <hip/hip_bf16.h>
#include <hip/hip_fp16.h>

typedef __hip_bfloat16 bf16;
typedef __attribute__((ext_vector_type(8))) short short8v;
typedef __attribute__((ext_vector_type(4))) float float4v;

#define V_    32000
#define E_    512
#define H_    512
#define T_    128
#define B_    4
#define D_    4
#define L_    2
#define C0_   2000
#define C1_   10000
#define NT_   125
#define NROW_ 2000          // B*NT*D
#define NH_   2002
#define NTOTC 2162          // 2002 + 128 + 32
#define NSLOT 252           // 17 head + 63 t0 + 172 t1 LSE partial slots per row

__device__ __forceinline__ float bf2f(bf16 v) { return __bfloat162float(v); }
__device__ __forceinline__ unsigned short f2bfu(float f) {
    bf16 h = __float2bfloat16(f);
    union { bf16 h; unsigned short u; } cv; cv.h = h; return cv.u;
}
// dtype-flag helpers: bf==1 -> bf16 input data, bf==0 -> float32
__device__ __forceinline__ float ld1(const void* p, size_t i, int bf) {
    return bf ? bf2f(((const bf16*)p)[i]) : ((const float*)p)[i];
}

__device__ __forceinline__ void lse_push(float z, float& m, float& s) {
    if (z <= m) { s += __expf(z - m); }
    else        { s = s * __expf(m - z) + 1.0f; m = z; }
}
__device__ __forceinline__ void lse_merge(float m2, float s2, float& m, float& s) {
    float mm = fmaxf(m, m2);
    s = s * __expf(m - mm) + s2 * __expf(m2 - mm);
    m = mm;
}

// ---------------- stage 0: dtype detect (G row 0 is a softmax row) --------
__global__ void k_detect(const void* __restrict__ G, int* __restrict__ flag) {
    int t = threadIdx.x;   // 64 threads
    float s32 = 0.0f;
    for (int k = t; k < 128; k += 64) s32 += ((const float*)G)[k];
    for (int off = 32; off; off >>= 1) s32 += __shfl_down(s32, off);
    if (t == 0) {
        float e32 = fabsf(s32 - 1.0f);
        *flag = (e32 < 0.05f) ? 0 : 1;   // NaN compares false -> bf16 fallback
    }
}

// ---------------- weight conversion + embedding gather (merged) -----------
// Conversion is 4-wide vectorized: every segment offset is a multiple of 4
// shorts, so a 4-group never straddles segments; bf16 source is a pure copy.
struct ConvArgs {
    const void* src[9];
    unsigned int off[10];
};
__global__ void k_wembed(ConvArgs a, unsigned short* __restrict__ wb,
                         const int* __restrict__ flagp,
                         const int* __restrict__ x, const void* __restrict__ emb,
                         float* __restrict__ embedded, float* __restrict__ f0,
                         unsigned short* __restrict__ f0b) {
    const int bf = *flagp;
    if (blockIdx.x < 1024) {
        // embedding gather: 262144 elements
        int i = blockIdx.x * 256 + threadIdx.x;
        int bt = i >> 9, e = i & 511;
        int tok = x[bt];
        float v = ld1(emb, (size_t)tok * E_ + e, bf);
        embedded[i] = v; f0[i] = v; f0b[i] = f2bfu(v);
    } else {
        unsigned int totalg = a.off[9] >> 2;          // groups of 4 shorts
        unsigned int stride = (gridDim.x - 1024) * 256;
        for (unsigned int g = (blockIdx.x - 1024) * 256 + threadIdx.x; g < totalg;
             g += stride) {
            unsigned int i = g << 2;
            int seg = 0;
            while (i >= a.off[seg + 1]) seg++;
            unsigned int o = i - a.off[seg];
            unsigned short r[4];
            if (bf) {
                *(uint2*)r = *(const uint2*)((const unsigned short*)a.src[seg] + o);
            } else {
                float4 v = *(const float4*)((const float*)a.src[seg] + o);
                r[0] = f2bfu(v.x); r[1] = f2bfu(v.y);
                r[2] = f2bfu(v.z); r[3] = f2bfu(v.w);
            }
            *(uint2*)(wb + i) = *(const uint2*)r;
        }
    }
}

// ---------------- wgt[b,i,e] = sum_j G[b,l,j,i] f[b,j,e] ------------------
__global__ void k_wgt(const void* __restrict__ G, const float* __restrict__ f,
                      unsigned short* __restrict__ wgtb, int l,
                      const int* __restrict__ flagp) {
    const int bf = *flagp;
    int i = blockIdx.x * 256 + threadIdx.x;          // 262144
    int e = i & 511;
    int bi = i >> 9;
    int b = bi >> 7, ip = bi & 127;
    size_t gbase = ((size_t)(b * L_ + l) * T_ * T_) + ip;
    const float* fb = f + (size_t)b * T_ * E_ + e;
    float acc = 0.0f;
    #pragma unroll 4
    for (int j = 0; j < T_; ++j)
        acc = fmaf(ld1(G, gbase + (size_t)j * T_, bf), fb[(size_t)j * E_], acc);
    wgtb[i] = f2bfu(acc);
}

// ---------------- MFMA bf16 GEMM core: Z[M,N] = A[M,K] * W[N,K]^T ---------
// MODE 0: gates   (store Z+bias into Zg at col zsel*zcol1; blockIdx.z picks A/W/bias)
// MODE 1: head single-pass (raw z -> out-in-place for cols<C0; LSE cols<2002 -> lsep;
//         stats 2000/2001; proj -> p0b/p1b)
// MODE 2: tail single-pass (raw z -> out-in-place at outColOff; LSE over all N)
// Raw-logit staging format: fp16 when final out dtype is bf16 (2B slots),
// fp32 when final out dtype is fp32 (4B slots) — d_out is exactly the right
// size in both modes, so no extra workspace and no flag-clobber hazard.
// lsep is slot-major [slot][row] so k_corr2 reads coalesce.
struct GemmP {
    const unsigned short* A0;
    const unsigned short* A1;
    const unsigned short* W;
    unsigned long long w1off;
    int M, N, K, Nlse;
    float* Zg; int ldz; int zcol1;
    const void* bias0; const void* bias1; int boff;
    void* zraw; int outColOff;
    float* stats;
    unsigned short* p0b;
    unsigned short* p1b;
    float* lsep; int slotBase;
    const int* lengths;
    const int* flagp;
    int gx;       // x-tile count of this segment (merged tail dispatch)
};

__device__ __forceinline__ void zstore(void* zraw, size_t i, int bf, float v) {
    if (bf) ((__half*)zraw)[i] = __float2half(v);
    else    ((float*)zraw)[i]  = v;
}

template<int MODE>
__device__ __forceinline__ void gemm_core(const GemmP& p, int bx, int by,
        unsigned short* As, unsigned short* Bs,
        float (*pm)[2], float (*ps)[2]) {
    const int bf = *p.flagp;
    const int zsel = (MODE == 0) ? blockIdx.z : 0;
    const unsigned short* A  = zsel ? p.A1 : p.A0;
    const unsigned short* Bw = p.W + (zsel ? p.w1off : 0ull);
    const int M = p.M, N = p.N, K = p.K;
    const int m0 = by * 128, n0 = bx * 128;
    const int t = threadIdx.x;
    const int wave = t >> 6, lane = t & 63;
    const int wm = wave >> 1, wn = wave & 1;
    const int quad = lane >> 4, l16 = lane & 15;

    float4v acc[4][4];
    #pragma unroll
    for (int mi = 0; mi < 4; ++mi)
        #pragma unroll
        for (int ni = 0; ni < 4; ++ni)
            acc[mi][ni] = (float4v){0.f, 0.f, 0.f, 0.f};

    for (int k0 = 0; k0 < K; k0 += 32) {
        if (k0) __syncthreads();
        #pragma unroll
        for (int i = 0; i < 2; ++i) {
            int idx = t + i * 256;
            int row = idx >> 2, seg = idx & 3;
            uint4 av = {0u, 0u, 0u, 0u};
            int gm = m0 + row;
            if (gm < M) av = *(const uint4*)(A + (size_t)gm * K + k0 + seg * 8);
            *(uint4*)(&As[row * 40 + seg * 8]) = av;
            uint4 bv = {0u, 0u, 0u, 0u};
            int gn = n0 + row;
            if (gn < N) bv = *(const uint4*)(Bw + (size_t)gn * K + k0 + seg * 8);
            *(uint4*)(&Bs[row * 40 + seg * 8]) = bv;
        }
        __syncthreads();
        short8v af[4], bfv[4];
        #pragma unroll
        for (int mi = 0; mi < 4; ++mi)
            af[mi] = *(const short8v*)(As + (wm * 64 + mi * 16 + l16) * 40 + quad * 8);
        #pragma unroll
        for (int ni = 0; ni < 4; ++ni)
            bfv[ni] = *(const short8v*)(Bs + (wn * 64 + ni * 16 + l16) * 40 + quad * 8);
        #pragma unroll
        for (int mi = 0; mi < 4; ++mi)
            #pragma unroll
            for (int ni = 0; ni < 4; ++ni)
                acc[mi][ni] = __builtin_amdgcn_mfma_f32_16x16x32_bf16(
                    af[mi], bfv[ni], acc[mi][ni], 0, 0, 0);
    }

    // ---- epilogue ----
    if (MODE == 0) {
        const void* bias = zsel ? p.bias1 : p.bias0;
        const int zcol = zsel ? p.zcol1 : 0;
        #pragma unroll
        for (int mi = 0; mi < 4; ++mi)
            #pragma unroll
            for (int r = 0; r < 4; ++r) {
                int grow = m0 + wm * 64 + mi * 16 + quad * 4 + r;
                if (grow >= M) continue;
                #pragma unroll
                for (int ni = 0; ni < 4; ++ni) {
                    int gcol = n0 + wn * 64 + ni * 16 + l16;
                    if (gcol < N)
                        p.Zg[(size_t)grow * p.ldz + zcol + gcol] =
                            acc[mi][ni][r] + ld1(bias, p.boff + gcol, bf);
                }
            }
    } else if (MODE == 1) {
        #pragma unroll
        for (int mi = 0; mi < 4; ++mi)
            #pragma unroll
            for (int r = 0; r < 4; ++r) {
                int grow = m0 + wm * 64 + mi * 16 + quad * 4 + r;
                if (grow >= M) continue;
                #pragma unroll
                for (int ni = 0; ni < 4; ++ni) {
                    int gcol = n0 + wn * 64 + ni * 16 + l16;
                    float v = acc[mi][ni][r];
                    if (gcol < C0_) zstore(p.zraw, (size_t)grow * V_ + gcol, bf, v);
                    else if (gcol < NH_) p.stats[grow * 8 + 2 + (gcol - C0_)] = v;
                    else if (gcol < 2130) p.p0b[grow * 128 + (gcol - NH_)] = f2bfu(v);
                    else if (gcol < NTOTC) p.p1b[grow * 32 + (gcol - 2130)] = f2bfu(v);
                }
            }
    } else {
        #pragma unroll
        for (int mi = 0; mi < 4; ++mi)
            #pragma unroll
            for (int r = 0; r < 4; ++r) {
                int grow = m0 + wm * 64 + mi * 16 + quad * 4 + r;
                if (grow >= M) continue;
                #pragma unroll
                for (int ni = 0; ni < 4; ++ni) {
                    int gcol = n0 + wn * 64 + ni * 16 + l16;
                    if (gcol < N)
                        zstore(p.zraw, (size_t)grow * V_ + p.outColOff + gcol, bf,
                               acc[mi][ni][r]);
                }
            }
    }

    // ---- fused per-tile LSE partials (single-pass modes) ----
    if (MODE == 1 || MODE == 2) {
        const int Nlse = p.Nlse;
        #pragma unroll
        for (int mi = 0; mi < 4; ++mi) {
            #pragma unroll
            for (int r = 0; r < 4; ++r) {
                float m = -1e30f, s = 0.0f;
                #pragma unroll
                for (int ni = 0; ni < 4; ++ni) {
                    int gcol = n0 + wn * 64 + ni * 16 + l16;
                    if (gcol < Nlse) lse_push(acc[mi][ni][r], m, s);
                }
                #pragma unroll
                for (int off = 1; off < 16; off <<= 1) {
                    float m2 = __shfl_xor(m, off), s2 = __shfl_xor(s, off);
                    lse_merge(m2, s2, m, s);
                }
                if (l16 == 0) {
                    int rl = wm * 64 + mi * 16 + quad * 4 + r;
                    pm[rl][wn] = m; ps[rl][wn] = s;
                }
            }
        }
        __syncthreads();
        if (t < 128) {
            int grow = m0 + t;
            if (grow < M) {
                float m = pm[t][0], s = ps[t][0];
                lse_merge(pm[t][1], ps[t][1], m, s);
                // slot-major layout: [slot][row]
                float* dst = p.lsep + ((size_t)(p.slotBase + bx) * NROW_ + grow) * 2;
                dst[0] = m; dst[1] = s;
            }
        }
    }
}

// __launch_bounds__(256, 2): 4 waves/block, min 2 waves/EU -> VGPR cap 256.
// Insurance against the r1 allocator heuristic that targeted 8 waves/EU
// (VGPR=64) and spilled the 64-VGPR accumulator tile to scratch.
template<int MODE>
__global__ __launch_bounds__(256, 2) void k_gemm(GemmP p) {
    __shared__ __align__(16) unsigned short As[128 * 40];
    __shared__ __align__(16) unsigned short Bs[128 * 40];
    __shared__ float pm[128][2], ps[128][2];
    gemm_core<MODE>(p, blockIdx.x, blockIdx.y, As, Bs, pm, ps);
}

// merged t0+t1 pass-A tail (both depend only on the head pass; independent
// of each other, so co-dispatch is race-free and fills the t0 tail).
__global__ __launch_bounds__(256, 2) void k_gemmT(GemmP pa, GemmP pb) {
    __shared__ __align__(16) unsigned short As[128 * 40];
    __shared__ __align__(16) unsigned short Bs[128 * 40];
    __shared__ float pm[128][2], ps[128][2];
    int bx = blockIdx.x;
    if (bx < pa.gx) gemm_core<2>(pa, bx, blockIdx.y, As, Bs, pm, ps);
    else            gemm_core<2>(pb, bx - pa.gx, blockIdx.y, As, Bs, pm, ps);
}

// ---------------- GRU pointwise ----------------
__device__ __forceinline__ float gru2(float i_r, float i_z, float i_n,
                                      float h_r, float h_z, float h_n, float h) {
    float r = 1.0f / (1.0f + __expf(-(i_r + h_r)));
    float z = 1.0f / (1.0f + __expf(-(i_z + h_z)));
    float n = tanhf(i_n + r * h_n);
    return (1.0f - z) * n + z * h;
}

__global__ void k_apply_enc(const float* __restrict__ gates,
                            const float* __restrict__ hprev,
                            float* __restrict__ hnext,
                            unsigned short* __restrict__ hnextb) {
    int i = blockIdx.x * 256 + threadIdx.x;          // 262144
    int row = i >> 9, k = i & 511;
    const float* g = gates + (size_t)row * 3072;
    float v = gru2(g[k], g[512 + k], g[1024 + k],
                   g[1536 + k], g[2048 + k], g[2560 + k], hprev[i]);
    hnext[i] = v; hnextb[i] = f2bfu(v);
}

// layer-1 apply fused with decoder prep: h0 init straight from the value in
// registers (blocks <1024) + window gather (blocks 1024..5023).
__global__ void k_apply_enc2(const float* __restrict__ gates,
                             const float* __restrict__ hprev,
                             float* __restrict__ hnext,
                             unsigned short* __restrict__ hnextb,
                             const float* __restrict__ embedded,
                             const int* __restrict__ lengths,
                             unsigned short* __restrict__ winb,
                             float* __restrict__ hdec,
                             unsigned short* __restrict__ hdecb) {
    int blk = blockIdx.x;
    if (blk < 1024) {
        int i = blk * 256 + threadIdx.x;             // 262144
        int row = i >> 9, k = i & 511;
        const float* g = gates + (size_t)row * 3072;
        float v = gru2(g[k], g[512 + k], g[1024 + k],
                       g[1536 + k], g[2048 + k], g[2560 + k], hprev[i]);
        hnext[i] = v; hnextb[i] = f2bfu(v);
        int b = row >> 7, t = row & 127;
        if (t < NT_) {
            int j = ((b * NT_ + t) << 9) + k;
            hdec[j] = v; hdecb[j] = f2bfu(v);
        }
    } else {
        int i = (blk - 1024) * 256 + threadIdx.x;    // 1,024,000
        int e = i & 511;
        int wr = i >> 9;
        int d = wr / 500, row = wr - d * 500;
        int b = row / NT_, t = row - b * NT_;
        int tok = (d == 0 && t == 0) ? (lengths[b] - 1) : (t + d - 1);
        winb[i] = f2bfu(embedded[((size_t)(b * T_ + tok) << 9) + e]);
    }
}

__global__ void k_apply_dec(const float* __restrict__ gih,
                            const float* __restrict__ ghh,
                            float* __restrict__ hdec,
                            unsigned short* __restrict__ hdecb,
                            unsigned short* __restrict__ hsb,
                            const int* __restrict__ lengths, int d) {
    int i = blockIdx.x * 256 + threadIdx.x;          // 256000
    int row = i >> 9, k = i & 511;
    int b = row / NT_, t = row - b * NT_;
    const float* gi = gih + (size_t)(d * 500 + row) * 1536;
    const float* gh = ghh + (size_t)row * 1536;
    float hn = gru2(gi[k], gi[512 + k], gi[1024 + k],
                    gh[k], gh[512 + k], gh[1024 + k], hdec[i]);
    hdec[i] = hn; hdecb[i] = f2bfu(hn);
    bool valid = (t + d) < lengths[b];
    hsb[(((size_t)row * D_ + d) << 9) + k] = valid ? f2bfu(hn) : (unsigned short)0;
}

// ---------------- combine LSE partials -> per-row corrections -------------
// lsep is slot-major: slot i, row r at lsep[(i*NROW_+r)*2] -> coalesced reads.
__global__ void k_corr2(const float* __restrict__ lsep, const float* __restrict__ stats,
                        float* __restrict__ corr) {
    int r = blockIdx.x * 256 + threadIdx.x;
    if (r >= NROW_) return;
    float m = -1e30f, s = 0.0f;
    for (int i = 0; i < 17; ++i) {
        const float* P = lsep + ((size_t)i * NROW_ + r) * 2;
        lse_merge(P[0], P[1], m, s);
    }
    float ch = m + logf(s);
    float lp0 = stats[r * 8 + 2] - ch;
    float lp1 = stats[r * 8 + 3] - ch;
    m = -1e30f; s = 0.0f;
    for (int i = 17; i < 80; ++i) {
        const float* P = lsep + ((size_t)i * NROW_ + r) * 2;
        lse_merge(P[0], P[1], m, s);
    }
    float ct0 = m + logf(s);
    m = -1e30f; s = 0.0f;
    for (int i = 80; i < 252; ++i) {
        const float* P = lsep + ((size_t)i * NROW_ + r) * 2;
        lse_merge(P[0], P[1], m, s);
    }
    float ct1 = m + logf(s);
    corr[r * 4 + 0] = ch;
    corr[r * 4 + 1] = ct0 - lp0;
    corr[r * 4 + 2] = ct1 - lp1;
}

// ------ in-place fixup: out[i] = valid ? zraw[i] - corr[seg] : 0 ----------
// Raw logits were staged into d_out itself (fp16 slots when out is bf16,
// fp32 slots when out is fp32). Each thread owns a disjoint 16/32-byte
// group (8 cols); segment boundaries 2000/10000 are multiples of 8 so a
// group never straddles segments. Per-thread read-then-write, no hazards.
__global__ void k_fix(const float* __restrict__ corr,
                      const int* __restrict__ lengths, void* __restrict__ out,
                      const int* __restrict__ flagp) {
    const int bf = *flagp;
    int idx = blockIdx.x * 256 + threadIdx.x;        // 8,000,000 groups
    if (idx >= NROW_ * (V_ / 8)) return;
    int row = idx / (V_ / 8);
    int col = (idx - row * (V_ / 8)) * 8;
    int b = row / 500;
    int tt = (row - b * 500) >> 2;
    bool valid = tt < lengths[b];
    int cri = (col < C0_) ? 0 : (col < C1_ ? 1 : 2);
    float cr = corr[row * 4 + cri];
    size_t base = (size_t)row * V_ + col;
    if (bf) {
        unsigned short* p16 = (unsigned short*)out + base;
        union { uint4 u; __half h[8]; } in;
        in.u = *(const uint4*)p16;
        union { uint4 u; unsigned short s[8]; } o;
        #pragma unroll
        for (int j = 0; j < 8; ++j)
            o.s[j] = f2bfu(valid ? (__half2float(in.h[j]) - cr) : 0.0f);
        *(uint4*)p16 = o.u;
    } else {
        float* op = (float*)out + base;
        float4 a = *(float4*)op, c = *(float4*)(op + 4);
        float4 ra = valid ? (float4){a.x - cr, a.y - cr, a.z - cr, a.w - cr}
                          : (float4){0.f, 0.f, 0.f, 0.f};
        float4 rc = valid ? (float4){c.x - cr, c.y - cr, c.z - cr, c.w - cr}
                          : (float4){0.f, 0.f, 0.f, 0.f};
        *(float4*)op = ra; *(float4*)(op + 4) = rc;
    }
}

// ---------------- workspace layout (float offsets, 16B aligned) -----------
#define OFF_EMB    0u          // 262144
#define OFF_FA     262144u     // 262144
#define OFF_FB     524288u     // 262144
#define OFF_FAB    786432u     // 131072 (262144 bf16)
#define OFF_FBB    917504u     // 131072
#define OFF_WGTB   1048576u    // 131072
#define OFF_GATES  1179648u    // 512*3072 = 1572864
#define OFF_GIH    2752512u    // 2000*1536 = 3072000
#define OFF_GHH    5824512u    // 500*1536 = 768000
#define OFF_HDEC   6592512u    // 256000
#define OFF_HDECB  6848512u    // 128000
#define OFF_WINB   6976512u    // 512000 (1,024,000 bf16)
#define OFF_HSB    7488512u    // 512000 (1,024,000 bf16)
#define OFF_P0B    8000512u    // 128000 (256000 bf16)
#define OFF_P1B    8128512u    // 32000  (64000 bf16)
#define OFF_STATS  8160512u    // 16000
#define OFF_CORR   8176512u    // 8000
#define OFF_LSEP   8184512u    // 1008000 (slot-major 252 x 2000 x 2)
#define OFF_WB     9192512u    // 3776752 (7553504 bf16)
#define OFF_FLAG   12969264u

// bf16 weight region sub-offsets (shorts)
#define WO_ENCIH   0u
#define WO_ENCHH   1572864u
#define WO_DECIH   3145728u
#define WO_DECHH   3932160u
#define WO_W1      4718592u    // head_w rows, t0_proj, t1_proj (2162x512)
#define WO_T0O     5825536u    // 8000x128
#define WO_T1O     6849536u    // 22000x32
#define WO_END     7553504u

static inline GemmP mkp(const unsigned short* A0, const unsigned short* A1,
                        const unsigned short* W, unsigned long long w1off,
                        int M, int N, int K, int Nlse,
                        float* Zg, int ldz, int zcol1,
                        const void* bias0, const void* bias1, int boff,
                        void* zraw, int outColOff, float* stats,
                        unsigned short* p0b, unsigned short* p1b,
                        float* lsep, int slotBase,
                        const int* lengths, const int* flagp) {
    GemmP p;
    p.A0 = A0; p.A1 = A1; p.W = W; p.w1off = w1off;
    p.M = M; p.N = N; p.K = K; p.Nlse = Nlse;
    p.Zg = Zg; p.ldz = ldz; p.zcol1 = zcol1;
    p.bias0 = bias0; p.bias1 = bias1; p.boff = boff;
    p.zraw = zraw; p.outColOff = outColOff; p.stats = stats;
    p.p0b = p0b; p.p1b = p1b; p.lsep = lsep; p.slotBase = slotBase;
    p.lengths = lengths; p.flagp = flagp; p.gx = 0;
    return p;
}

extern "C" void kernel_launch(void* const* d_in, const int* in_sizes, int n_in,
                              void* d_out, int out_size, void* d_ws, size_t ws_size,
                              hipStream_t stream) {
    (void)in_sizes; (void)n_in; (void)out_size; (void)ws_size;
    const int*  x        = (const int*)d_in[0];
    const int*  lengths  = (const int*)d_in[1];
    const void* G        = d_in[2];
    const void* emb      = d_in[3];
    const void* enc_w_ih = d_in[4];
    const void* enc_w_hh = d_in[5];
    const void* enc_b_ih = d_in[6];
    const void* enc_b_hh = d_in[7];
    const void* dec_w_ih = d_in[8];
    const void* dec_w_hh = d_in[9];
    const void* dec_b_ih = d_in[10];
    const void* dec_b_hh = d_in[11];
    const void* head_w   = d_in[12];
    const void* t0_proj  = d_in[13];
    const void* t0_out   = d_in[14];
    const void* t1_proj  = d_in[15];
    const void* t1_out   = d_in[16];

    float* ws = (float*)d_ws;
    float* embedded = ws + OFF_EMB;
    float* fA    = ws + OFF_FA;
    float* fB    = ws + OFF_FB;
    unsigned short* fAb  = (unsigned short*)(ws + OFF_FAB);
    unsigned short* fBb  = (unsigned short*)(ws + OFF_FBB);
    unsigned short* wgtb = (unsigned short*)(ws + OFF_WGTB);
    float* gates = ws + OFF_GATES;
    float* gih   = ws + OFF_GIH;
    float* ghh   = ws + OFF_GHH;
    float* hdec  = ws + OFF_HDEC;
    unsigned short* hdecb = (unsigned short*)(ws + OFF_HDECB);
    unsigned short* winb  = (unsigned short*)(ws + OFF_WINB);
    unsigned short* hsb   = (unsigned short*)(ws + OFF_HSB);
    unsigned short* p0b   = (unsigned short*)(ws + OFF_P0B);
    unsigned short* p1b   = (unsigned short*)(ws + OFF_P1B);
    float* stats = ws + OFF_STATS;
    float* corr  = ws + OFF_CORR;
    float* lsep  = ws + OFF_LSEP;
    unsigned short* WB = (unsigned short*)(ws + OFF_WB);
    int* flagp = (int*)(ws + OFF_FLAG);
    void* out = d_out;

    k_detect<<<1, 64, 0, stream>>>(G, flagp);

    ConvArgs ca;
    ca.src[0] = enc_w_ih; ca.src[1] = enc_w_hh; ca.src[2] = dec_w_ih;
    ca.src[3] = dec_w_hh; ca.src[4] = head_w;   ca.src[5] = t0_proj;
    ca.src[6] = t1_proj;  ca.src[7] = t0_out;   ca.src[8] = t1_out;
    ca.off[0] = WO_ENCIH; ca.off[1] = WO_ENCHH; ca.off[2] = WO_DECIH;
    ca.off[3] = WO_DECHH; ca.off[4] = WO_W1;
    ca.off[5] = WO_W1 + 2002u * 512u;
    ca.off[6] = WO_W1 + 2130u * 512u;
    ca.off[7] = WO_T0O;   ca.off[8] = WO_T1O;   ca.off[9] = WO_END;
    k_wembed<<<3072, 256, 0, stream>>>(ca, WB, flagp, x, emb, embedded, fA, fAb);

    // encoder layer 0: fA -> fB  (ih + hh fused via gridDim.z)
    k_wgt<<<1024, 256, 0, stream>>>(G, fA, wgtb, 0, flagp);
    k_gemm<0><<<dim3(12, 4, 2), 256, 0, stream>>>(mkp(
        wgtb, fAb, WB + WO_ENCIH, (unsigned long long)(WO_ENCHH - WO_ENCIH),
        512, 1536, 512, 0, gates, 3072, 1536, enc_b_ih, enc_b_hh, 0,
        nullptr, 0, nullptr, nullptr, nullptr, nullptr, 0, lengths, flagp));
    k_apply_enc<<<1024, 256, 0, stream>>>(gates, fA, fB, fBb);

    // encoder layer 1: fB -> fA, fused with decoder prep (h0 + window gather)
    k_wgt<<<1024, 256, 0, stream>>>(G, fB, wgtb, 1, flagp);
    k_gemm<0><<<dim3(12, 4, 2), 256, 0, stream>>>(mkp(
        wgtb, fBb, WB + WO_ENCIH + 786432u, (unsigned long long)(WO_ENCHH - WO_ENCIH),
        512, 1536, 512, 0, gates, 3072, 1536, enc_b_ih, enc_b_hh, 1536,
        nullptr, 0, nullptr, nullptr, nullptr, nullptr, 0, lengths, flagp));
    k_apply_enc2<<<5024, 256, 0, stream>>>(gates, fB, fA, fAb, embedded, lengths,
                                           winb, hdec, hdecb);

    // batched decoder ih GEMM (all 4 d-steps at once)
    k_gemm<0><<<dim3(12, 16, 1), 256, 0, stream>>>(mkp(
        winb, nullptr, WB + WO_DECIH, 0ull, 2000, 1536, 512, 0,
        gih, 1536, 0, dec_b_ih, nullptr, 0,
        nullptr, 0, nullptr, nullptr, nullptr, nullptr, 0, lengths, flagp));

    // serial decoder hh steps
    for (int d = 0; d < D_; ++d) {
        k_gemm<0><<<dim3(12, 4, 1), 256, 0, stream>>>(mkp(
            hdecb, nullptr, WB + WO_DECHH, 0ull, 500, 1536, 512, 0,
            ghh, 1536, 0, dec_b_hh, nullptr, 0,
            nullptr, 0, nullptr, nullptr, nullptr, nullptr, 0, lengths, flagp));
        k_apply_dec<<<1000, 256, 0, stream>>>(gih, ghh, hdec, hdecb, hsb, lengths, d);
    }

    // adaptive softmax — single pass: head (raw logits + stats + projections
    // + LSE partials), then t0+t1 tails merged into one dispatch
    k_gemm<1><<<dim3(17, 16, 1), 256, 0, stream>>>(mkp(
        hsb, nullptr, WB + WO_W1, 0ull, NROW_, NTOTC, 512, NH_,
        nullptr, 0, 0, nullptr, nullptr, 0, out, 0,
        stats, p0b, p1b, lsep, 0, lengths, flagp));
    {
        GemmP pa = mkp(p0b, nullptr, WB + WO_T0O, 0ull, NROW_, 8000, 128, 8000,
                       nullptr, 0, 0, nullptr, nullptr, 0, out, C0_,
                       stats, nullptr, nullptr, lsep, 17, lengths, flagp);
        pa.gx = 63;
        GemmP pb = mkp(p1b, nullptr, WB + WO_T1O, 0ull, NROW_, 22000, 32, 22000,
                       nullptr, 0, 0, nullptr, nullptr, 0, out, C1_,
                       stats, nullptr, nullptr, lsep, 80, lengths, flagp);
        pb.gx = 172;
        k_gemmT<<<dim3(235, 16, 1), 256, 0, stream>>>(pa, pb);
    }

    k_corr2<<<8, 256, 0, stream>>>(lsep, stats, corr);

    // in-place fixup: out = valid ? z - corr : 0  (replaces pass-B GEMMs)
    k_fix<<<31250, 256, 0, stream>>>(corr, lengths, out, flagp);
}